// Round 1
// baseline (49.430 us; speedup 1.0000x reference)
//
#include <hip/hip_runtime.h>

// Exact-rounding 3-component squared sum in reference order: (x*x + y*y) + z*z
static __device__ __forceinline__ float sq3(float x, float y, float z) {
    return __fadd_rn(__fadd_rn(__fmul_rn(x, x), __fmul_rn(y, y)), __fmul_rn(z, z));
}

__global__ __launch_bounds__(256) void hb_kernel(
    const float* __restrict__ X,
    const int*   __restrict__ C,
    const int*   __restrict__ E,
    const float* __restrict__ M,
    float* __restrict__ outHB,
    float* __restrict__ outMK,
    float* __restrict__ outH,
    int N, int rows)
{
    const float EPS   = 0.001f;
    const float COEFF = (float)(0.42 * 0.2 * 332.0);   // 27.888f, same rounding as python
    const float LENNH = 1.015f;

    int tid = blockIdx.x * blockDim.x + threadIdx.x;
    int row = tid >> 6;                 // b*N + i
    if (row >= rows) return;
    int k = tid & 63;
    int i = row & (N - 1);              // N is 16384 (power of two)
    int b = row >> 14;

    // ---- per-row H_i (redundant across lanes; same-address broadcast loads) ----
    const float* xi = X + (size_t)row * 12;
    float nx = xi[0], ny = xi[1], nz = xi[2];
    float cax = xi[3], cay = xi[4], caz = xi[5];
    int prow = (i == 0) ? row : row - 1;
    const float* xp = X + (size_t)prow * 12;
    float px = xp[6], py = xp[7], pz = xp[8];

    // u1 = normed(N - Cprev): v / sqrt(sum(v*v)+eps), per-component DIVISION
    float ax = __fsub_rn(nx, px), ay = __fsub_rn(ny, py), az = __fsub_rn(nz, pz);
    float s1 = __fsqrt_rn(__fadd_rn(sq3(ax, ay, az), EPS));
    ax = __fdiv_rn(ax, s1); ay = __fdiv_rn(ay, s1); az = __fdiv_rn(az, s1);
    // u2 = normed(N - Ca)
    float bx = __fsub_rn(nx, cax), by = __fsub_rn(ny, cay), bz = __fsub_rn(nz, caz);
    float s2 = __fsqrt_rn(__fadd_rn(sq3(bx, by, bz), EPS));
    bx = __fdiv_rn(bx, s2); by = __fdiv_rn(by, s2); bz = __fdiv_rn(bz, s2);
    // u = normed(u1 + u2)
    float ux = __fadd_rn(ax, bx), uy = __fadd_rn(ay, by), uz = __fadd_rn(az, bz);
    float s3 = __fsqrt_rn(__fadd_rn(sq3(ux, uy, uz), EPS));
    ux = __fdiv_rn(ux, s3); uy = __fdiv_rn(uy, s3); uz = __fdiv_rn(uz, s3);
    float hx = __fadd_rn(nx, __fmul_rn(LENNH, ux));
    float hy = __fadd_rn(ny, __fmul_rn(LENNH, uy));
    float hz = __fadd_rn(nz, __fmul_rn(LENNH, uz));

    if (k == 0) {
        float* ho = outH + (size_t)row * 3;
        ho[0] = hx; ho[1] = hy; ho[2] = hz;
    }

    // ---- per-edge work ----
    size_t eoff = (size_t)row * 64 + (size_t)k;
    int j = E[eoff];
    float mij = M[eoff];

    const float* xj = X + ((size_t)b * (size_t)N + (size_t)j) * 12;
    // atoms 2 (C_j) and 3 (O_j): floats [6..11]; 48j+24 is 8B-aligned, 48j+32 is 16B-aligned
    float2 cj01 = *(const float2*)(xj + 6);
    float4 v4   = *(const float4*)(xj + 8);
    float cjx = cj01.x, cjy = cj01.y, cjz = v4.x;
    float ojx = v4.y,   ojy = v4.z,   ojz = v4.w;

    // D_NO and invD(N,O) share the same d2
    float dx = __fsub_rn(nx, ojx), dy = __fsub_rn(ny, ojy), dz = __fsub_rn(nz, ojz);
    float dno = __fsqrt_rn(__fadd_rn(sq3(dx, dy, dz), EPS));
    float iNO = __fdiv_rn(1.0f, dno);
    dx = __fsub_rn(nx, cjx); dy = __fsub_rn(ny, cjy); dz = __fsub_rn(nz, cjz);
    float iNC = __fdiv_rn(1.0f, __fsqrt_rn(__fadd_rn(sq3(dx, dy, dz), EPS)));
    dx = __fsub_rn(hx, cjx); dy = __fsub_rn(hy, cjy); dz = __fsub_rn(hz, cjz);
    float iHC = __fdiv_rn(1.0f, __fsqrt_rn(__fadd_rn(sq3(dx, dy, dz), EPS)));
    dx = __fsub_rn(hx, ojx); dy = __fsub_rn(hy, ojy); dz = __fsub_rn(hz, ojz);
    float iHO = __fdiv_rn(1.0f, __fsqrt_rn(__fadd_rn(sq3(dx, dy, dz), EPS)));

    // U = COEFF * (((iNO - iNC) + iHC) - iHO)  -- reference left-to-right order
    float U = __fmul_rn(COEFF, __fsub_rn(__fadd_rn(__fsub_rn(iNO, iNC), iHC), iHO));

    int Ci = C[row];
    int Cn = C[(size_t)b * (size_t)N + (size_t)j];
    int dij = j - i; if (dij < 0) dij = -dij;

    float m_local    = ((dij < 3) && (Ci == Cn)) ? 1.0f : 0.0f;
    float m_nonlocal = __fsub_rn(1.0f, m_local);
    float m_cutD     = (dno < 3.6f) ? 1.0f : 0.0f;
    // reference: C_prev == C exactly (concat-zeros then [:,1:] is identity), so mask_i = (C>0)
    float m_i        = (Ci > 0) ? 1.0f : 0.0f;
    float m_int      = __fmul_rn(m_i, (Cn > 0) ? 1.0f : 0.0f);

    float mhb = __fmul_rn(__fmul_rn(__fmul_rn(mij, m_nonlocal), m_cutD), m_int);
    float hb  = __fmul_rn(mhb, (U < -0.5f) ? 1.0f : 0.0f);

    outHB[eoff] = hb;
    outMK[eoff] = mhb;
}

extern "C" void kernel_launch(void* const* d_in, const int* in_sizes, int n_in,
                              void* d_out, int out_size, void* d_ws, size_t ws_size,
                              hipStream_t stream) {
    const float* X = (const float*)d_in[0];
    const int*   C = (const int*)d_in[1];
    const int*   E = (const int*)d_in[2];
    const float* M = (const float*)d_in[3];

    int rows = in_sizes[1];          // B*N = 65536
    int BNK  = in_sizes[2];          // B*N*K = 4194304
    const int N = 16384;

    float* out   = (float*)d_out;
    float* outHB = out;
    float* outMK = out + (size_t)BNK;
    float* outH  = out + 2 * (size_t)BNK;

    int total = rows * 64;           // one lane per (row, k)
    int block = 256;
    int grid  = (total + block - 1) / block;
    hipLaunchKernelGGL(hb_kernel, dim3(grid), dim3(block), 0, stream,
                       X, C, E, M, outHB, outMK, outH, N, rows);
}